// Round 8
// baseline (276.677 us; speedup 1.0000x reference)
//
#include <hip/hip_runtime.h>
#include <math.h>

typedef _Float16 h8 __attribute__((ext_vector_type(8)));
typedef float    f4v __attribute__((ext_vector_type(4)));

#define N_TRAIN 400000
#define DIMS    27
#define BQ      512
#define NCLS    11
#define KNN     3
#define NB      500            // pass-1 blocks
#define TPB     512            // pass-1 threads (8 waves)
#define PTS_BLK 800            // points per block (500*800 = 400000 exact)
#define PTS_SUP 160            // points per super-tile (10 ptiles)
#define NSUP    5
#define NPT     10
#define RAWF    4320           // floats per super-tile (160*27)
#define TILE_B  2048           // conv bytes per ptile: hi 1024 + lo 1024
#define NC      (NB * KNN)     // candidates per query (1500)
#define SB      512            // k_scale blocks
#define RPB     784            // rows per k_scale block (784*27*4 % 16 == 0)
#define SROWS   128

// ---------------- scale pass A: per-block column maxima (no atomics, no pre-zero) ----------------
__global__ __launch_bounds__(256) void k_scale(const float* __restrict__ train,
                                               float* __restrict__ partial) {
    __shared__ float st[SROWS * DIMS];
    __shared__ float sp[243];
    int tid = threadIdx.x;
    int r0 = blockIdx.x * RPB;
    int r1 = min(r0 + RPB, N_TRAIN);
    int c  = tid % DIMS;
    int rr = tid / DIMS;
    float m = 0.f;
    for (int base = r0; base < r1; base += SROWS) {
        int cnt = min(SROWS, r1 - base);     // multiple of 4
        int tot4 = (cnt * DIMS) >> 2;
        const uint4* src4 = (const uint4*)(train + (size_t)base * DIMS); // 16B aligned
        uint4* st4 = (uint4*)st;
        for (int i = tid; i < tot4; i += 256) st4[i] = src4[i];
        __syncthreads();
        if (tid < 243) {
            for (int r = rr; r < cnt; r += 9)
                m = fmaxf(m, fabsf(st[r * DIMS + c]));
        }
        __syncthreads();
    }
    if (tid < 243) sp[tid] = m;
    __syncthreads();
    if (tid < DIMS) {
        float v = 0.f;
#pragma unroll
        for (int g = 0; g < 9; ++g) v = fmaxf(v, sp[g * DIMS + tid]);
        partial[blockIdx.x * 32 + tid] = v;
    }
}

// ---------------- scale pass B + query prep ----------------
// Reduce 512 partials -> scale_f; build split-f16 B-fragments (k=27 slot = {1,0}).
__global__ __launch_bounds__(TPB) void k_qprep(const float* __restrict__ query,
                                               const float* __restrict__ partial,
                                               float* __restrict__ scale_f,
                                               _Float16* __restrict__ Qhi,
                                               _Float16* __restrict__ Qlo) {
    __shared__ float red[16][32];
    __shared__ float s_inv[32];
    int tid = threadIdx.x;
    int c = tid & 31, g = tid >> 5;          // 32 cols x 16 groups
    float m = 0.f;
    for (int b = g; b < SB; b += 16) m = fmaxf(m, partial[b * 32 + c]);
    red[g][c] = m;
    __syncthreads();
    if (tid < 32) {
        float v = red[0][tid];
#pragma unroll
        for (int gg = 1; gg < 16; ++gg) v = fmaxf(v, red[gg][tid]);
        if (tid >= DIMS) v = 0.f;
        scale_f[tid] = v;
        s_inv[tid] = (v != 0.f) ? 1.f / v : 0.f;   // divide_no_nan
    }
    __syncthreads();

    int q = tid;                              // 512 threads == 512 queries
    const float* r = query + (size_t)q * DIMS;
#pragma unroll
    for (int d = 0; d < 32; ++d) {
        _Float16 hi = (_Float16)0.f, lo = (_Float16)0.f;
        if (d < DIMS) {
            float xs = r[d] * s_inv[d];
            hi = (_Float16)xs;
            lo = (_Float16)(xs - (float)hi);
        } else if (d == 27) {
            hi = (_Float16)1.f;               // multiplies A's -xn/2 hi+lo slots
        }
        Qhi[q * 32 + d] = hi;
        Qlo[q * 32 + d] = lo;
    }
}

// batch-max over 4 candidates (eq-select keeps earliest on ties), then branchless
// top-2 insert (strict >: earlier incumbent wins ties).
#define BMAX4_TOP2(A0, A1, A2, A3, G0, G1, G2, G3, B0, B1, I0, I1) do { \
    float m_ = fmaxf(fmaxf(A0, A1), fmaxf(A2, A3)); \
    int gm_ = (m_ == (A0)) ? (G0) : (m_ == (A1)) ? (G1) : (m_ == (A2)) ? (G2) : (G3); \
    bool c0_ = m_ > (B0); \
    bool c1_ = m_ > (B1); \
    B1 = c0_ ? (B0) : (c1_ ? m_ : (B1)); \
    I1 = c0_ ? (I0) : (c1_ ? gm_ : (I1)); \
    B0 = c0_ ? m_ : (B0); \
    I0 = c0_ ? gm_ : (I0); \
} while (0)

// lexicographic (key, idx) insert into ascending sorted triple — matches top_k ties
__device__ __forceinline__ void insert3(float d, int i, float* bd, int* bi) {
    if (d < bd[2] || (d == bd[2] && i < bi[2])) {
        if (d < bd[1] || (d == bd[1] && i < bi[1])) {
            bd[2] = bd[1]; bi[2] = bi[1];
            if (d < bd[0] || (d == bd[0] && i < bi[0])) {
                bd[1] = bd[0]; bi[1] = bi[0];
                bd[0] = d; bi[0] = i;
            } else { bd[1] = d; bi[1] = i; }
        } else { bd[2] = d; bi[2] = i; }
    }
}

// lexicographic insert into sorted 8
__device__ __forceinline__ void ins8(float d, int i, float* bd, int* bi) {
    if (!(d < bd[7] || (d == bd[7] && i < bi[7]))) return;
#pragma unroll
    for (int k = 7; k >= 1; --k) {
        if (d < bd[k - 1] || (d == bd[k - 1] && i < bi[k - 1])) {
            bd[k] = bd[k - 1]; bi[k] = bi[k - 1];
        } else { bd[k] = d; bi[k] = i; return; }
    }
    bd[0] = d; bi[0] = i;
}

__device__ __forceinline__ void stage16(const float* g, float* l) {
    __builtin_amdgcn_global_load_lds((const __attribute__((address_space(1))) void*)g,
                                     (__attribute__((address_space(3))) void*)l, 16, 0, 0);
}

// ---------------- pass 1: split-f16 MFMA (xn folded) + batch-max top-2 ----------------
__global__ __attribute__((amdgpu_flat_work_group_size(TPB, TPB)))
__attribute__((amdgpu_waves_per_eu(4, 4)))
void k_pass1(const float* __restrict__ train,
             const float* __restrict__ scale_f,
             const _Float16* __restrict__ Qhi,
             const _Float16* __restrict__ Qlo,
             float* __restrict__ cand_d,
             int* __restrict__ cand_i) {
    __shared__ float s_inv[32];
    __shared__ __align__(16) float raw[2][RAWF];
    __shared__ __align__(16) unsigned char conv[NPT * TILE_B];

    int tid = threadIdx.x;
    if (tid < 32) {
        float sc = scale_f[tid];              // 0 for d>=27
        s_inv[tid] = (sc != 0.f) ? 1.f / sc : 0.f;
    }
    int lane = tid & 63, w = tid >> 6;
    int l15 = lane & 15, quad = lane >> 4;

    h8 bhi[4], blo[4];
#pragma unroll
    for (int j = 0; j < 4; ++j) {
        int qt = w * 4 + j;
        size_t e = (size_t)(qt * 16 + l15) * 32 + quad * 8;
        bhi[j] = *(const h8*)(Qhi + e);
        blo[j] = *(const h8*)(Qlo + e);
    }

    float b0[4], b1[4];
    int   i0[4], i1[4];
#pragma unroll
    for (int j = 0; j < 4; ++j) { b0[j] = -3.4e38f; b1[j] = -3.4e38f; i0[j] = 0x7fffffff; i1[j] = 0x7fffffff; }

    int p0 = blockIdx.x * PTS_BLK;
    const float* gsup = train + (size_t)p0 * DIMS;   // 16B aligned

    {   // async stage super-tile 0
        const float* gp = gsup; float* lp = raw[0];
        stage16(gp + tid * 4, lp + tid * 4);
        stage16(gp + 2048 + tid * 4, lp + 2048 + tid * 4);
        if (tid < 56) stage16(gp + 4096 + tid * 4, lp + 4096 + tid * 4);
    }

    for (int s = 0; s < NSUP; ++s) {
        __syncthreads();   // drains vmcnt -> raw[s] ready; conv free

        const float* rw = raw[s & 1];
#pragma unroll
        for (int pass = 0; pass < 2; ++pass) {
            int task = tid + pass * TPB;
            if (task < PTS_SUP * 4) {
                int p = task >> 2, gq = task & 3;
                float x[8]; float part = 0.f;
#pragma unroll
                for (int i = 0; i < 8; ++i) {
                    int d = gq * 8 + i;
                    int dc = d < DIMS ? d : (DIMS - 1);     // clamp; s_inv[d>=27]=0
                    float v = rw[p * DIMS + dc] * s_inv[d];
                    x[i] = v;
                    part = fmaf(v, v, part);
                }
                part += __shfl_xor(part, 1, 64);
                part += __shfl_xor(part, 2, 64);
                h8 hv, lv;
#pragma unroll
                for (int i = 0; i < 8; ++i) {
                    _Float16 h = (_Float16)x[i];
                    hv[i] = h;
                    lv[i] = (_Float16)(x[i] - (float)h);
                }
                if (gq == 3) {                              // slot i=3 is k=27: -xn/2 split
                    float tt = -0.5f * part;
                    _Float16 th = (_Float16)tt;
                    hv[3] = th;
                    lv[3] = (_Float16)(tt - (float)th);
                }
                unsigned char* dstb = conv + (p >> 4) * TILE_B + gq * 256 + (p & 15) * 16;
                *(h8*)dstb = hv;
                *(h8*)(dstb + 1024) = lv;
            }
        }
        __syncthreads();   // conv ready

        if (s + 1 < NSUP) {   // async stage next super-tile during compute
            const float* gp = gsup + (size_t)(s + 1) * RAWF;
            float* lp = raw[(s + 1) & 1];
            stage16(gp + tid * 4, lp + tid * 4);
            stage16(gp + 2048 + tid * 4, lp + 2048 + tid * 4);
            if (tid < 56) stage16(gp + 4096 + tid * 4, lp + 4096 + tid * 4);
        }

        for (int t = 0; t < NPT; ++t) {
            const unsigned char* basep = conv + t * TILE_B;
            h8 ahi = *(const h8*)(basep + lane * 16);       // lane-linear: conflict-free
            h8 alo = *(const h8*)(basep + 1024 + lane * 16);
            int gb = p0 + (s * NPT + t) * 16 + quad * 4;
            int g0 = gb, g1 = gb + 1, g2 = gb + 2, g3 = gb + 3;
#pragma unroll
            for (int j = 0; j < 4; ++j) {
                f4v acc = {0.f, 0.f, 0.f, 0.f};
                acc = __builtin_amdgcn_mfma_f32_16x16x32_f16(alo, bhi[j], acc, 0, 0, 0);
                acc = __builtin_amdgcn_mfma_f32_16x16x32_f16(ahi, blo[j], acc, 0, 0, 0);
                acc = __builtin_amdgcn_mfma_f32_16x16x32_f16(ahi, bhi[j], acc, 0, 0, 0);
                BMAX4_TOP2(acc[0], acc[1], acc[2], acc[3], g0, g1, g2, g3,
                           b0[j], b1[j], i0[j], i1[j]);
            }
        }
    }

    // cross-quad merge -> block top-3 per query, keys = -acc; block-owned layout
    int g = blockIdx.x;
#pragma unroll
    for (int j = 0; j < 4; ++j) {
        float kk[3] = {-b0[j], -b1[j], 3.4e38f};
        int   ii[3] = {i0[j], i1[j], 0x7fffffff};
#pragma unroll
        for (int step = 16; step <= 32; step <<= 1) {
            float od[3]; int oi[3];
#pragma unroll
            for (int k = 0; k < 3; ++k) {
                od[k] = __shfl_xor(kk[k], step, 64);
                oi[k] = __shfl_xor(ii[k], step, 64);
            }
#pragma unroll
            for (int k = 0; k < 3; ++k) insert3(od[k], oi[k], kk, ii);
        }
        if (quad == 0) {
            int qq = (w * 4 + j) * 16 + l15;
            size_t off = ((size_t)g * BQ + qq) * KNN;   // [block][query][3]: block-owned lines
#pragma unroll
            for (int k = 0; k < KNN; ++k) { cand_d[off + k] = kk[k]; cand_i[off + k] = ii[k]; }
        }
    }
}

// ---------------- pass 2: approx top-8 merge -> exact f32 refine -> vote ----------------
__global__ __launch_bounds__(64) void k_pass2(const float* __restrict__ cand_d,
                                              const int* __restrict__ cand_i,
                                              const float* __restrict__ train,
                                              const float* __restrict__ query,
                                              const float* __restrict__ scale_f,
                                              const float* __restrict__ labels,
                                              float* __restrict__ out) {
    int q = blockIdx.x, lane = threadIdx.x;

    float d8[8]; int i8v[8];
#pragma unroll
    for (int k = 0; k < 8; ++k) { d8[k] = 3.4e38f; i8v[k] = 0x7fffffff; }
    for (int gb = lane; gb < NB; gb += 64) {
        size_t off = ((size_t)gb * BQ + q) * KNN;
#pragma unroll
        for (int k = 0; k < KNN; ++k) ins8(cand_d[off + k], cand_i[off + k], d8, i8v);
    }

#pragma unroll
    for (int step = 1; step < 64; step <<= 1) {
        float od[8]; int oi[8];
#pragma unroll
        for (int k = 0; k < 8; ++k) {
            od[k] = __shfl_xor(d8[k], step, 64);
            oi[k] = __shfl_xor(i8v[k], step, 64);
        }
#pragma unroll
        for (int k = 0; k < 8; ++k) ins8(od[k], oi[k], d8, i8v);
    }
    // all lanes hold identical global approx top-8

    // exact f32 scaled query + qn (verified R1 op order)
    float inv[DIMS], qs_[DIMS], qn_ = 0.f;
#pragma unroll
    for (int d = 0; d < DIMS; ++d) {
        float sc = scale_f[d];
        float iv = (sc != 0.f) ? 1.f / sc : 0.f;
        float v = query[(size_t)q * DIMS + d] * iv;
        inv[d] = iv; qs_[d] = v;
        qn_ = fmaf(v, v, qn_);
    }

    int myi = 0x7fffffff;
#pragma unroll
    for (int k = 0; k < 8; ++k) if (lane == k) myi = i8v[k];
    float myd2 = 3.4e38f;
    if (lane < 8) {
        const float* r = train + (size_t)myi * DIMS;
        float xnv = 0.f, dot = 0.f;
#pragma unroll
        for (int d = 0; d < DIMS; ++d) {
            float v = r[d] * inv[d];
            xnv = fmaf(v, v, xnv);
            dot = fmaf(qs_[d], v, dot);
        }
        myd2 = fmaf(-2.f, dot, qn_ + xnv);
    }

    float bd[KNN] = {3.4e38f, 3.4e38f, 3.4e38f};
    int   bi[KNN] = {0x7fffffff, 0x7fffffff, 0x7fffffff};
#pragma unroll
    for (int k = 0; k < 8; ++k) {
        float dk = __shfl(myd2, k, 64);
        int   ik = __shfl(myi, k, 64);
        insert3(dk, ik, bd, bi);
    }

    if (lane == 0) {
        float kd[KNN];
#pragma unroll
        for (int k = 0; k < KNN; ++k) kd[k] = sqrtf(fmaxf(bd[k], 0.f));
        float lab[KNN][NCLS];
#pragma unroll
        for (int k = 0; k < KNN; ++k) {
            const float* lr = labels + (size_t)bi[k] * NCLS;
#pragma unroll
            for (int c = 0; c < NCLS; ++c) lab[k][c] = lr[c];
        }
        float votes[NCLS];
#pragma unroll
        for (int c = 0; c < NCLS; ++c) votes[c] = 0.f;
#pragma unroll
        for (int k = 0; k < KNN; ++k) {
            float ks = (kd[k] == 0.f) ? 1.f : kd[k];
#pragma unroll
            for (int c = 0; c < NCLS; ++c) votes[c] += lab[k][c] / ks;
        }
        int best = 0; float bv = votes[0];
#pragma unroll
        for (int c = 1; c < NCLS; ++c) { if (votes[c] > bv) { bv = votes[c]; best = c; } }
        bool zero_hit = (kd[0] == 0.f);
#pragma unroll
        for (int k = 0; k < KNN; ++k) out[(size_t)q * KNN + k] = kd[k];
        float* ro = out + (size_t)BQ * KNN + (size_t)q * NCLS;
#pragma unroll
        for (int c = 0; c < NCLS; ++c)
            ro[c] = zero_hit ? lab[0][c] : ((c == best) ? 1.f : 0.f);
    }
}

extern "C" void kernel_launch(void* const* d_in, const int* in_sizes, int n_in,
                              void* d_out, int out_size, void* d_ws, size_t ws_size,
                              hipStream_t stream) {
    const float* query  = (const float*)d_in[0];
    const float* train  = (const float*)d_in[1];
    const float* labels = (const float*)d_in[2];
    float* out = (float*)d_out;

    // ws layout:
    //   [0)       partial: 512*32 f32 (65536 B)
    //   [65536)   scale_f: 32 f32 (128 B)
    //   [65664)   Qhi: 512*32 f16 (32768 B)
    //   [98432)   Qlo: 512*32 f16 (32768 B)
    //   [131200)  cand_d: 500*512*3 f32 (3072000 B)
    //   [3203200) cand_i: 500*512*3 i32 (3072000 B)   total ~6.3 MB
    char* ws = (char*)d_ws;
    float*     partial = (float*)ws;
    float*     scale_f = (float*)(ws + 65536);
    _Float16*  Qhi = (_Float16*)(ws + 65664);
    _Float16*  Qlo = (_Float16*)(ws + 98432);
    float*     cand_d = (float*)(ws + 131200);
    int*       cand_i = (int*)(ws + 3203200);

    k_scale<<<SB, 256, 0, stream>>>(train, partial);
    k_qprep<<<1, TPB, 0, stream>>>(query, partial, scale_f, Qhi, Qlo);
    k_pass1<<<NB, TPB, 0, stream>>>(train, scale_f, Qhi, Qlo, cand_d, cand_i);
    k_pass2<<<BQ, 64, 0, stream>>>(cand_d, cand_i, train, query, scale_f, labels, out);
}

// Round 9
// 246.624 us; speedup vs baseline: 1.1219x; 1.1219x over previous
//
#include <hip/hip_runtime.h>
#include <math.h>

typedef _Float16 h8 __attribute__((ext_vector_type(8)));
typedef float    f4v __attribute__((ext_vector_type(4)));

#define N_TRAIN 400000
#define DIMS    27
#define BQ      512
#define NCLS    11
#define KNN     3
#define NB      500            // pass-1 blocks
#define TPB     512            // pass-1 threads (8 waves)
#define PTS_BLK 800            // points per block (500*800 = 400000 exact)
#define PTS_SUP 160            // points per super-tile (10 ptiles)
#define NSUP    5
#define NPT     10
#define TILE_B  2048           // packed bytes per 16-pt tile: hi 1024 + lo 1024
#define SUP_B   (NPT * TILE_B) // 20480 B per supertile
#define RAWF    4320           // floats per super-tile (160*27), fallback path
#define NC      (NB * KNN)     // candidates per query (1500)
#define SB      512            // k_scale blocks
#define RPB     784            // rows per k_scale block
#define SROWS   128
#define XPACK_OFF  6211584ull  // 2048-aligned
#define XPACK_SIZE 51200000ull // 25000 tiles * 2048 B
#define WS_NEED    (XPACK_OFF + XPACK_SIZE)

// ---------------- scale = max(|train|, axis=0) ----------------
__global__ __launch_bounds__(256) void k_scale(const float* __restrict__ train,
                                               unsigned* __restrict__ scale_u) {
    __shared__ float st[SROWS * DIMS];
    __shared__ float sp[243];
    int tid = threadIdx.x;
    int r0 = blockIdx.x * RPB;
    int r1 = min(r0 + RPB, N_TRAIN);
    int c  = tid % DIMS;
    int rr = tid / DIMS;
    float m = 0.f;
    for (int base = r0; base < r1; base += SROWS) {
        int cnt = min(SROWS, r1 - base);     // multiple of 4
        int tot4 = (cnt * DIMS) >> 2;
        const uint4* src4 = (const uint4*)(train + (size_t)base * DIMS);
        uint4* st4 = (uint4*)st;
        for (int i = tid; i < tot4; i += 256) st4[i] = src4[i];
        __syncthreads();
        if (tid < 243) {
            for (int r = rr; r < cnt; r += 9)
                m = fmaxf(m, fabsf(st[r * DIMS + c]));
        }
        __syncthreads();
    }
    if (tid < 243) sp[tid] = m;
    __syncthreads();
    if (tid < DIMS) {
        float v = 0.f;
#pragma unroll
        for (int g = 0; g < 9; ++g) v = fmaxf(v, sp[g * DIMS + tid]);
        atomicMax(&scale_u[tid], __float_as_uint(v)); // values >= 0: uint order == float order
    }
}

// ---------------- query prep: split-f16 B-fragments, k=27 slot = {1,0} ----------------
__global__ __launch_bounds__(256) void k_qprep(const float* __restrict__ query,
                                               const unsigned* __restrict__ scale_u,
                                               _Float16* __restrict__ Qhi,
                                               _Float16* __restrict__ Qlo) {
    int q = blockIdx.x * 256 + threadIdx.x;
    if (q >= BQ) return;
    const float* r = query + (size_t)q * DIMS;
#pragma unroll
    for (int d = 0; d < 32; ++d) {
        _Float16 hi = (_Float16)0.f, lo = (_Float16)0.f;
        if (d < DIMS) {
            float sc = __uint_as_float(scale_u[d]);
            float inv = (sc != 0.f) ? 1.f / sc : 0.f;   // divide_no_nan
            float xs = r[d] * inv;
            hi = (_Float16)xs;
            lo = (_Float16)(xs - (float)hi);
        } else if (d == 27) {
            hi = (_Float16)1.f;   // multiplies A's -xn/2 hi+lo slots
        }
        Qhi[q * 32 + d] = hi;
        Qlo[q * 32 + d] = lo;
    }
}

// ---------------- train preconvert: packed [tile][kblock][point] hi/lo, -xn/2 at k=27 ----------------
// Block = 256 thr, 64 points. Task = (point p, kblock gq): exactly 256 tasks.
__global__ __launch_bounds__(256) void k_conv(const float* __restrict__ train,
                                              const unsigned* __restrict__ scale_u,
                                              unsigned char* __restrict__ xpack) {
    __shared__ float st[64 * DIMS];     // 6912 B
    __shared__ float s_inv[32];
    int tid = threadIdx.x;
    if (tid < 32) {
        float sc = __uint_as_float(scale_u[tid]);   // 0 for d>=27
        s_inv[tid] = (sc != 0.f) ? 1.f / sc : 0.f;
    }
    const uint4* src4 = (const uint4*)(train + (size_t)blockIdx.x * 64 * DIMS); // 6912 B, 16B aligned
    uint4* st4 = (uint4*)st;
    if (tid < 216) { st4[tid] = src4[tid]; st4[tid + 216] = src4[tid + 216]; }
    __syncthreads();

    int p = tid >> 2, gq = tid & 3;
    float x[8]; float part = 0.f;
#pragma unroll
    for (int i = 0; i < 8; ++i) {
        int d = gq * 8 + i;
        int dc = d < DIMS ? d : (DIMS - 1);   // clamp; s_inv[d>=27]=0 zeroes value
        float v = st[p * DIMS + dc] * s_inv[d];
        x[i] = v;
        part = fmaf(v, v, part);
    }
    part += __shfl_xor(part, 1, 64);
    part += __shfl_xor(part, 2, 64);          // 4 lanes of a point all hold xn
    h8 hv, lv;
#pragma unroll
    for (int i = 0; i < 8; ++i) {
        _Float16 h = (_Float16)x[i];
        hv[i] = h;
        lv[i] = (_Float16)(x[i] - (float)h);
    }
    if (gq == 3) {                            // slot i=3 is k=27: -xn/2 split
        float tt = -0.5f * part;
        _Float16 th = (_Float16)tt;
        hv[3] = th;
        lv[3] = (_Float16)(tt - (float)th);
    }
    size_t tbase = ((size_t)blockIdx.x * 4 + (p >> 4)) * TILE_B;
    unsigned char* dst = xpack + tbase + gq * 256 + (p & 15) * 16;
    *(h8*)dst = hv;
    *(h8*)(dst + 1024) = lv;
}

// batch-max over 4 candidates (eq-select keeps earliest on ties) + branchless top-2
#define BMAX4_TOP2(A0, A1, A2, A3, G0, G1, G2, G3, B0, B1, I0, I1) do { \
    float m_ = fmaxf(fmaxf(A0, A1), fmaxf(A2, A3)); \
    int gm_ = (m_ == (A0)) ? (G0) : (m_ == (A1)) ? (G1) : (m_ == (A2)) ? (G2) : (G3); \
    bool c0_ = m_ > (B0); \
    bool c1_ = m_ > (B1); \
    B1 = c0_ ? (B0) : (c1_ ? m_ : (B1)); \
    I1 = c0_ ? (I0) : (c1_ ? gm_ : (I1)); \
    B0 = c0_ ? m_ : (B0); \
    I0 = c0_ ? gm_ : (I0); \
} while (0)

// lexicographic (key, idx) insert into ascending sorted triple — matches top_k ties
__device__ __forceinline__ void insert3(float d, int i, float* bd, int* bi) {
    if (d < bd[2] || (d == bd[2] && i < bi[2])) {
        if (d < bd[1] || (d == bd[1] && i < bi[1])) {
            bd[2] = bd[1]; bi[2] = bi[1];
            if (d < bd[0] || (d == bd[0] && i < bi[0])) {
                bd[1] = bd[0]; bi[1] = bi[0];
                bd[0] = d; bi[0] = i;
            } else { bd[1] = d; bi[1] = i; }
        } else { bd[2] = d; bi[2] = i; }
    }
}

// lexicographic insert into sorted 8
__device__ __forceinline__ void ins8(float d, int i, float* bd, int* bi) {
    if (!(d < bd[7] || (d == bd[7] && i < bi[7]))) return;
#pragma unroll
    for (int k = 7; k >= 1; --k) {
        if (d < bd[k - 1] || (d == bd[k - 1] && i < bi[k - 1])) {
            bd[k] = bd[k - 1]; bi[k] = bi[k - 1];
        } else { bd[k] = d; bi[k] = i; return; }
    }
    bd[0] = d; bi[0] = i;
}

__device__ __forceinline__ void stage16(const void* g, void* l) {
    __builtin_amdgcn_global_load_lds((const __attribute__((address_space(1))) void*)g,
                                     (__attribute__((address_space(3))) void*)l, 16, 0, 0);
}

// shared epilogue: cross-quad merge -> block top-3 per query -> [query][block] store
__device__ __forceinline__ void merge_store(float* b0, float* b1, int* i0, int* i1,
                                            int w, int l15, int quad, int g,
                                            float* cand_d, int* cand_i) {
#pragma unroll
    for (int j = 0; j < 4; ++j) {
        float kk[3] = {-b0[j], -b1[j], 3.4e38f};
        int   ii[3] = {i0[j], i1[j], 0x7fffffff};
#pragma unroll
        for (int step = 16; step <= 32; step <<= 1) {
            float od[3]; int oi[3];
#pragma unroll
            for (int k = 0; k < 3; ++k) {
                od[k] = __shfl_xor(kk[k], step, 64);
                oi[k] = __shfl_xor(ii[k], step, 64);
            }
#pragma unroll
            for (int k = 0; k < 3; ++k) insert3(od[k], oi[k], kk, ii);
        }
        if (quad == 0) {
            int qq = (w * 4 + j) * 16 + l15;
            size_t off = (size_t)qq * NC + (size_t)g * KNN;   // [query][block] (R7 layout)
#pragma unroll
            for (int k = 0; k < KNN; ++k) { cand_d[off + k] = kk[k]; cand_i[off + k] = ii[k]; }
        }
    }
}

// ---------------- pass 1 (packed): stage xpack supertiles, pure MFMA + select ----------------
__global__ __launch_bounds__(TPB)
void k_pass1p(const unsigned char* __restrict__ xpack,
              const _Float16* __restrict__ Qhi,
              const _Float16* __restrict__ Qlo,
              float* __restrict__ cand_d,
              int* __restrict__ cand_i) {
    __shared__ __align__(16) unsigned char xb[2][SUP_B];   // 40960 B

    int tid = threadIdx.x;
    int lane = tid & 63, w = tid >> 6;
    int l15 = lane & 15, quad = lane >> 4;

    h8 bhi[4], blo[4];
#pragma unroll
    for (int j = 0; j < 4; ++j) {
        int qt = w * 4 + j;
        size_t e = (size_t)(qt * 16 + l15) * 32 + quad * 8;
        bhi[j] = *(const h8*)(Qhi + e);
        blo[j] = *(const h8*)(Qlo + e);
    }

    float b0[4], b1[4];
    int   i0[4], i1[4];
#pragma unroll
    for (int j = 0; j < 4; ++j) { b0[j] = -3.4e38f; b1[j] = -3.4e38f; i0[j] = 0x7fffffff; i1[j] = 0x7fffffff; }

    int p0 = blockIdx.x * PTS_BLK;
    const unsigned char* gbase = xpack + (size_t)blockIdx.x * (NSUP * SUP_B);

    {   // stage supertile 0
        const unsigned char* gp = gbase;
        stage16(gp + tid * 16, xb[0] + tid * 16);
        stage16(gp + 8192 + tid * 16, xb[0] + 8192 + tid * 16);
        if (tid < 256) stage16(gp + 16384 + tid * 16, xb[0] + 16384 + tid * 16);
    }

    for (int s = 0; s < NSUP; ++s) {
        __syncthreads();   // drains stage(s); all waves done with xb[(s+1)&1] (compute s-1)

        if (s + 1 < NSUP) {   // stage next supertile; flies during compute(s)
            const unsigned char* gp = gbase + (size_t)(s + 1) * SUP_B;
            unsigned char* lp = xb[(s + 1) & 1];
            stage16(gp + tid * 16, lp + tid * 16);
            stage16(gp + 8192 + tid * 16, lp + 8192 + tid * 16);
            if (tid < 256) stage16(gp + 16384 + tid * 16, lp + 16384 + tid * 16);
        }

        const unsigned char* buf = xb[s & 1];
        for (int t = 0; t < NPT; ++t) {
            const unsigned char* basep = buf + t * TILE_B;
            h8 ahi = *(const h8*)(basep + lane * 16);       // lane-linear: conflict-free
            h8 alo = *(const h8*)(basep + 1024 + lane * 16);
            int gb = p0 + (s * NPT + t) * 16 + quad * 4;
#pragma unroll
            for (int j = 0; j < 4; ++j) {
                f4v acc = {0.f, 0.f, 0.f, 0.f};
                acc = __builtin_amdgcn_mfma_f32_16x16x32_f16(alo, bhi[j], acc, 0, 0, 0);
                acc = __builtin_amdgcn_mfma_f32_16x16x32_f16(ahi, blo[j], acc, 0, 0, 0);
                acc = __builtin_amdgcn_mfma_f32_16x16x32_f16(ahi, bhi[j], acc, 0, 0, 0);
                BMAX4_TOP2(acc[0], acc[1], acc[2], acc[3], gb, gb + 1, gb + 2, gb + 3,
                           b0[j], b1[j], i0[j], i1[j]);
            }
        }
    }
    merge_store(b0, b1, i0, i1, w, l15, quad, blockIdx.x, cand_d, cand_i);
}

// ---------------- pass 1 (fallback, inline convert — R8 structure, R7 layout) ----------------
__global__ __launch_bounds__(TPB)
void k_pass1f(const float* __restrict__ train,
              const unsigned* __restrict__ scale_u,
              const _Float16* __restrict__ Qhi,
              const _Float16* __restrict__ Qlo,
              float* __restrict__ cand_d,
              int* __restrict__ cand_i) {
    __shared__ float s_inv[32];
    __shared__ __align__(16) float raw[2][RAWF];
    __shared__ __align__(16) unsigned char conv[NPT * TILE_B];

    int tid = threadIdx.x;
    if (tid < 32) {
        float sc = __uint_as_float(scale_u[tid]);
        s_inv[tid] = (sc != 0.f) ? 1.f / sc : 0.f;
    }
    int lane = tid & 63, w = tid >> 6;
    int l15 = lane & 15, quad = lane >> 4;

    h8 bhi[4], blo[4];
#pragma unroll
    for (int j = 0; j < 4; ++j) {
        int qt = w * 4 + j;
        size_t e = (size_t)(qt * 16 + l15) * 32 + quad * 8;
        bhi[j] = *(const h8*)(Qhi + e);
        blo[j] = *(const h8*)(Qlo + e);
    }
    float b0[4], b1[4];
    int   i0[4], i1[4];
#pragma unroll
    for (int j = 0; j < 4; ++j) { b0[j] = -3.4e38f; b1[j] = -3.4e38f; i0[j] = 0x7fffffff; i1[j] = 0x7fffffff; }

    int p0 = blockIdx.x * PTS_BLK;
    const float* gsup = train + (size_t)p0 * DIMS;
    {
        const float* gp = gsup; float* lp = raw[0];
        stage16(gp + tid * 4, lp + tid * 4);
        stage16(gp + 2048 + tid * 4, lp + 2048 + tid * 4);
        if (tid < 56) stage16(gp + 4096 + tid * 4, lp + 4096 + tid * 4);
    }
    for (int s = 0; s < NSUP; ++s) {
        __syncthreads();
        const float* rw = raw[s & 1];
#pragma unroll
        for (int pass = 0; pass < 2; ++pass) {
            int task = tid + pass * TPB;
            if (task < PTS_SUP * 4) {
                int p = task >> 2, gq = task & 3;
                float x[8]; float part = 0.f;
#pragma unroll
                for (int i = 0; i < 8; ++i) {
                    int d = gq * 8 + i;
                    int dc = d < DIMS ? d : (DIMS - 1);
                    float v = rw[p * DIMS + dc] * s_inv[d];
                    x[i] = v;
                    part = fmaf(v, v, part);
                }
                part += __shfl_xor(part, 1, 64);
                part += __shfl_xor(part, 2, 64);
                h8 hv, lv;
#pragma unroll
                for (int i = 0; i < 8; ++i) {
                    _Float16 h = (_Float16)x[i];
                    hv[i] = h;
                    lv[i] = (_Float16)(x[i] - (float)h);
                }
                if (gq == 3) {
                    float tt = -0.5f * part;
                    _Float16 th = (_Float16)tt;
                    hv[3] = th;
                    lv[3] = (_Float16)(tt - (float)th);
                }
                unsigned char* dstb = conv + (p >> 4) * TILE_B + gq * 256 + (p & 15) * 16;
                *(h8*)dstb = hv;
                *(h8*)(dstb + 1024) = lv;
            }
        }
        __syncthreads();
        if (s + 1 < NSUP) {
            const float* gp = gsup + (size_t)(s + 1) * RAWF;
            float* lp = raw[(s + 1) & 1];
            stage16(gp + tid * 4, lp + tid * 4);
            stage16(gp + 2048 + tid * 4, lp + 2048 + tid * 4);
            if (tid < 56) stage16(gp + 4096 + tid * 4, lp + 4096 + tid * 4);
        }
        for (int t = 0; t < NPT; ++t) {
            const unsigned char* basep = conv + t * TILE_B;
            h8 ahi = *(const h8*)(basep + lane * 16);
            h8 alo = *(const h8*)(basep + 1024 + lane * 16);
            int gb = p0 + (s * NPT + t) * 16 + quad * 4;
#pragma unroll
            for (int j = 0; j < 4; ++j) {
                f4v acc = {0.f, 0.f, 0.f, 0.f};
                acc = __builtin_amdgcn_mfma_f32_16x16x32_f16(alo, bhi[j], acc, 0, 0, 0);
                acc = __builtin_amdgcn_mfma_f32_16x16x32_f16(ahi, blo[j], acc, 0, 0, 0);
                acc = __builtin_amdgcn_mfma_f32_16x16x32_f16(ahi, bhi[j], acc, 0, 0, 0);
                BMAX4_TOP2(acc[0], acc[1], acc[2], acc[3], gb, gb + 1, gb + 2, gb + 3,
                           b0[j], b1[j], i0[j], i1[j]);
            }
        }
    }
    merge_store(b0, b1, i0, i1, w, l15, quad, blockIdx.x, cand_d, cand_i);
}

// ---------------- pass 2: approx top-8 merge -> exact f32 refine -> vote ----------------
__global__ __launch_bounds__(64) void k_pass2(const float* __restrict__ cand_d,
                                              const int* __restrict__ cand_i,
                                              const float* __restrict__ train,
                                              const float* __restrict__ query,
                                              const unsigned* __restrict__ scale_u,
                                              const float* __restrict__ labels,
                                              float* __restrict__ out) {
    int q = blockIdx.x, lane = threadIdx.x;
    const float* cd = cand_d + (size_t)q * NC;
    const int*   ci = cand_i + (size_t)q * NC;

    float d8[8]; int i8v[8];
#pragma unroll
    for (int k = 0; k < 8; ++k) { d8[k] = 3.4e38f; i8v[k] = 0x7fffffff; }
    for (int c = lane; c < NC; c += 64) ins8(cd[c], ci[c], d8, i8v);

#pragma unroll
    for (int step = 1; step < 64; step <<= 1) {
        float od[8]; int oi[8];
#pragma unroll
        for (int k = 0; k < 8; ++k) {
            od[k] = __shfl_xor(d8[k], step, 64);
            oi[k] = __shfl_xor(i8v[k], step, 64);
        }
#pragma unroll
        for (int k = 0; k < 8; ++k) ins8(od[k], oi[k], d8, i8v);
    }
    // all lanes hold identical global approx top-8

    float inv[DIMS], qs_[DIMS], qn_ = 0.f;
#pragma unroll
    for (int d = 0; d < DIMS; ++d) {
        float sc = __uint_as_float(scale_u[d]);
        float iv = (sc != 0.f) ? 1.f / sc : 0.f;
        float v = query[(size_t)q * DIMS + d] * iv;
        inv[d] = iv; qs_[d] = v;
        qn_ = fmaf(v, v, qn_);
    }

    int myi = 0x7fffffff;
#pragma unroll
    for (int k = 0; k < 8; ++k) if (lane == k) myi = i8v[k];
    float myd2 = 3.4e38f;
    if (lane < 8) {
        const float* r = train + (size_t)myi * DIMS;
        float xnv = 0.f, dot = 0.f;
#pragma unroll
        for (int d = 0; d < DIMS; ++d) {
            float v = r[d] * inv[d];
            xnv = fmaf(v, v, xnv);
            dot = fmaf(qs_[d], v, dot);
        }
        myd2 = fmaf(-2.f, dot, qn_ + xnv);   // identical to verified R1 formula
    }

    float bd[KNN] = {3.4e38f, 3.4e38f, 3.4e38f};
    int   bi[KNN] = {0x7fffffff, 0x7fffffff, 0x7fffffff};
#pragma unroll
    for (int k = 0; k < 8; ++k) {
        float dk = __shfl(myd2, k, 64);
        int   ik = __shfl(myi, k, 64);
        insert3(dk, ik, bd, bi);
    }

    if (lane == 0) {
        float kd[KNN];
#pragma unroll
        for (int k = 0; k < KNN; ++k) kd[k] = sqrtf(fmaxf(bd[k], 0.f));
        float lab[KNN][NCLS];
#pragma unroll
        for (int k = 0; k < KNN; ++k) {
            const float* lr = labels + (size_t)bi[k] * NCLS;
#pragma unroll
            for (int c = 0; c < NCLS; ++c) lab[k][c] = lr[c];
        }
        float votes[NCLS];
#pragma unroll
        for (int c = 0; c < NCLS; ++c) votes[c] = 0.f;
#pragma unroll
        for (int k = 0; k < KNN; ++k) {
            float ks = (kd[k] == 0.f) ? 1.f : kd[k];
#pragma unroll
            for (int c = 0; c < NCLS; ++c) votes[c] += lab[k][c] / ks;
        }
        int best = 0; float bv = votes[0];
#pragma unroll
        for (int c = 1; c < NCLS; ++c) { if (votes[c] > bv) { bv = votes[c]; best = c; } }
        bool zero_hit = (kd[0] == 0.f);
#pragma unroll
        for (int k = 0; k < KNN; ++k) out[(size_t)q * KNN + k] = kd[k];
        float* ro = out + (size_t)BQ * KNN + (size_t)q * NCLS;
#pragma unroll
        for (int c = 0; c < NCLS; ++c)
            ro[c] = zero_hit ? lab[0][c] : ((c == best) ? 1.f : 0.f);
    }
}

extern "C" void kernel_launch(void* const* d_in, const int* in_sizes, int n_in,
                              void* d_out, int out_size, void* d_ws, size_t ws_size,
                              hipStream_t stream) {
    const float* query  = (const float*)d_in[0];
    const float* train  = (const float*)d_in[1];
    const float* labels = (const float*)d_in[2];
    float* out = (float*)d_out;

    // ws layout:
    //   [0)        scale_u: 32 u32 (128 B, memset 0)
    //   [128)      Qhi: 512*32 f16 (32768 B)
    //   [32896)    Qlo: 512*32 f16 (32768 B)
    //   [65664)    cand_d: 512*1500 f32 (3072000 B)
    //   [3137664)  cand_i: 512*1500 i32 (3072000 B)
    //   [6211584)  xpack: 25000 tiles * 2048 B = 51.2 MB (packed-path only)
    char* ws = (char*)d_ws;
    unsigned*      scale_u = (unsigned*)ws;
    _Float16*      Qhi = (_Float16*)(ws + 128);
    _Float16*      Qlo = (_Float16*)(ws + 32896);
    float*         cand_d = (float*)(ws + 65664);
    int*           cand_i = (int*)(ws + 3137664);
    unsigned char* xpack = (unsigned char*)(ws + XPACK_OFF);

    hipMemsetAsync(ws, 0, 128, stream);   // zero scale accumulators
    k_scale<<<SB, 256, 0, stream>>>(train, scale_u);
    k_qprep<<<2, 256, 0, stream>>>(query, scale_u, Qhi, Qlo);
    if (ws_size >= WS_NEED) {
        k_conv<<<N_TRAIN / 64, 256, 0, stream>>>(train, scale_u, xpack);
        k_pass1p<<<NB, TPB, 0, stream>>>(xpack, Qhi, Qlo, cand_d, cand_i);
    } else {
        k_pass1f<<<NB, TPB, 0, stream>>>(train, scale_u, Qhi, Qlo, cand_d, cand_i);
    }
    k_pass2<<<BQ, 64, 0, stream>>>(cand_d, cand_i, train, query, scale_u, labels, out);
}